// Round 5
// baseline (302.499 us; speedup 1.0000x reference)
//
#include <hip/hip_runtime.h>
#include <hip/hip_bf16.h>

#define N_NODES 50000
#define N_EDGES 800000
#define IN_F 256
#define HEADS 8
#define OUT_F 32
#define HF (HEADS * OUT_F)   // 256
#define SLOPE 0.2f

typedef __attribute__((ext_vector_type(8))) short bf16x8;
typedef __attribute__((ext_vector_type(4))) float f32x4;

__device__ __forceinline__ ushort f2bf(float f) {
  union { float f; unsigned u; } x;
  x.f = f;
  unsigned r = x.u + 0x7FFFu + ((x.u >> 16) & 1u);  // RNE
  return (ushort)(r >> 16);
}
__device__ __forceinline__ float bf2f_lo(unsigned u) {
  union { unsigned u; float f; } x; x.u = u << 16; return x.f;
}
__device__ __forceinline__ float bf2f_hi(unsigned u) {
  union { unsigned u; float f; } x; x.u = u & 0xFFFF0000u; return x.f;
}
__device__ __forceinline__ unsigned pkbf(float a, float b) {
  __hip_bfloat162 t = __float22bfloat162_rn(make_float2(a, b));
  return *(unsigned*)&t;  // low ushort = a, high = b
}

// ---------------------------------------------------------------------------
// Kernel 1: Bt[n][k] = bf16(fc_w[k][n])  (256x256, tiny)
// ---------------------------------------------------------------------------
__global__ void transpose_w(const float* __restrict__ fc_w,
                            ushort* __restrict__ Bt) {
  const int n = blockIdx.x, k = threadIdx.x;
  Bt[n * IN_F + k] = f2bf(fc_w[(size_t)k * HF + n]);
}

// ---------------------------------------------------------------------------
// Kernel 2: CSR row_ptr from sorted dst via binary search
// ---------------------------------------------------------------------------
__global__ void rowptr_kernel(const int* __restrict__ dst,
                              int* __restrict__ row_ptr, int N, int E) {
  int i = blockIdx.x * blockDim.x + threadIdx.x;
  if (i > N) return;
  int lo = 0, hi = E;
  while (lo < hi) {
    int mid = (lo + hi) >> 1;
    if (dst[mid] < i) lo = mid + 1; else hi = mid;
  }
  row_ptr[i] = lo;
}

// ---------------------------------------------------------------------------
// Kernel 3: register-resident-B MFMA GEMM, no LDS, no barriers.
// featb[M,256](bf16) = bf16( feat[M,256](f32) @ Bt^T ).
// Block = 512 thr = 8 waves; wave owns cols [gy*128 + wave*16, +16) with the
// whole K=256 B-slice in 32 VGPRs. m-strip of 128 rows per block; A rows are
// read once per col-group directly from fp32 with packed cvt.
// ---------------------------------------------------------------------------
__global__ __launch_bounds__(512) void gemm_regB(
    const float* __restrict__ feat, const ushort* __restrict__ Bt,
    ushort* __restrict__ Cb, int M) {
  const int t = threadIdx.x;
  const int wave = t >> 6, lane = t & 63;
  const int l16 = lane & 15, q = lane >> 4;
  const int n_base = blockIdx.y * 128 + wave * 16;

  // B fragments: lane (l16,q) holds B[k = kk*32 + q*8 + j][n = n_base+l16]
  bf16x8 bF[8];
#pragma unroll
  for (int kk = 0; kk < 8; ++kk)
    bF[kk] = *(const bf16x8*)&Bt[(size_t)(n_base + l16) * IN_F + kk * 32 + q * 8];

  const int m_strip = blockIdx.x * 128;
#pragma unroll 1
  for (int mi = 0; mi < 8; ++mi) {
    const int m0 = m_strip + mi * 16;
    const int row = m0 + l16;
    const float* ap = &feat[(size_t)row * IN_F + q * 8];
    f32x4 acc = {};
#pragma unroll
    for (int kk = 0; kk < 8; ++kk) {
      float4 a0 = make_float4(0.f, 0.f, 0.f, 0.f);
      float4 a1 = make_float4(0.f, 0.f, 0.f, 0.f);
      if (row < M) {
        a0 = *(const float4*)(ap + kk * 32);
        a1 = *(const float4*)(ap + kk * 32 + 4);
      }
      union { unsigned u[4]; bf16x8 v; } pk;
      pk.u[0] = pkbf(a0.x, a0.y);
      pk.u[1] = pkbf(a0.z, a0.w);
      pk.u[2] = pkbf(a1.x, a1.y);
      pk.u[3] = pkbf(a1.z, a1.w);
      acc = __builtin_amdgcn_mfma_f32_16x16x32_bf16(pk.v, bF[kk], acc, 0, 0, 0);
    }
    // C/D layout: col = l16, row = q*4 + r
#pragma unroll
    for (int r = 0; r < 4; ++r) {
      const int orow = m0 + q * 4 + r;
      if (orow < M)
        Cb[(size_t)orow * HF + n_base + l16] = f2bf(acc[r]);
    }
  }
}

// ---------------------------------------------------------------------------
// Kernel 4: el[n,h] = sum_f bf16(feat_src)[n,h,f] * attn_l[h,f]
// ---------------------------------------------------------------------------
__global__ __launch_bounds__(256) void scores_kernel(
    const ushort* __restrict__ featb, const float* __restrict__ attn_l,
    float* __restrict__ el, int NH) {
  const int idx = blockIdx.x * blockDim.x + threadIdx.x;
  if (idx >= NH) return;
  const int h = idx & 7;
  const ushort* fp = &featb[(size_t)(idx >> 3) * HF + h * OUT_F];
  const float* ap = &attn_l[h * OUT_F];
  float acc = 0.f;
#pragma unroll
  for (int fq = 0; fq < OUT_F; fq += 8) {
    uint4 d = *(const uint4*)&fp[fq];
    float4 w0 = *(const float4*)&ap[fq];
    float4 w1 = *(const float4*)&ap[fq + 4];
    acc += bf2f_lo(d.x) * w0.x + bf2f_hi(d.x) * w0.y +
           bf2f_lo(d.y) * w0.z + bf2f_hi(d.y) * w0.w +
           bf2f_lo(d.z) * w1.x + bf2f_hi(d.z) * w1.y +
           bf2f_lo(d.w) * w1.z + bf2f_hi(d.w) * w1.w;
  }
  el[idx] = acc;
}

// ---------------------------------------------------------------------------
// Kernel 5: aggregation, one wave per node, zero barriers.
// Lane mapping (softmax phases): h = lane&7, edge-slot eg = lane>>3 (8 edges
// per pass). Feature pass: half-wave reads one 512 B featb row per step
// (2 edges per instruction), facc[8] per lane, shfl-combine at the end.
// ---------------------------------------------------------------------------
#define AGG_CAP 64

__global__ __launch_bounds__(256) void aggregate_kernel(
    const ushort* __restrict__ featb, const float* __restrict__ el,
    const int* __restrict__ src, const int* __restrict__ row_ptr,
    float* __restrict__ out) {
  __shared__ float s_alpha[4][AGG_CAP][HEADS];  // 8 KB, per-wave private
  __shared__ int s_srcw[4][AGG_CAP];            // 1 KB, per-wave private

  const int t = threadIdx.x, w = t >> 6, lane = t & 63;
  const int v = blockIdx.x * 4 + w;
  if (v >= N_NODES) return;

  const int beg = row_ptr[v];
  const int deg = row_ptr[v + 1] - beg;
  const int fo = (lane & 31) * 8;  // 8-elem feature slice owned in facc

  if (deg == 0) {
    if (lane < 32) {
      float4 z = make_float4(0.f, 0.f, 0.f, 0.f);
      *(float4*)&out[(size_t)v * HF + fo] = z;
      *(float4*)&out[(size_t)v * HF + fo + 4] = z;
    }
    return;
  }

  const int h = lane & 7, eg = lane >> 3;

  // Phase 1: running max of el over incoming edges (8 edges/pass)
  float mx = -1e30f;
  for (int p = 0; p * 8 < deg; ++p) {
    const int e = p * 8 + eg;
    if (e < deg) {
      const int s = src[beg + e];
      mx = fmaxf(mx, el[s * HEADS + h]);
    }
  }
  mx = fmaxf(mx, __shfl_xor(mx, 8, 64));
  mx = fmaxf(mx, __shfl_xor(mx, 16, 64));
  mx = fmaxf(mx, __shfl_xor(mx, 32, 64));

  // Phase 2: chunked alpha + feature accumulation (normalize at the end)
  const int half = lane >> 5;
  const int myh = (lane & 31) >> 2;  // head of this lane's facc slice
  float facc[8] = {};
  float ssum = 0.f;

  for (int c0 = 0; c0 < deg; c0 += AGG_CAP) {
    const int cn = min(AGG_CAP, deg - c0);
    for (int p = 0; p * 8 < cn; ++p) {
      const int e = p * 8 + eg;
      if (e < cn) {
        const int s = src[beg + c0 + e];
        const float z = el[s * HEADS + h] - mx;
        const float zz = (z >= 0.f) ? z : SLOPE * z;
        const float cf = __expf(zz);
        ssum += cf;
        s_alpha[w][e][h] = cf;
        if (h == 0) s_srcw[w][e] = s;
      }
    }
    int cpad = cn;
    if (cn & 1) {  // pad to even: alpha=0, src=0 contributes nothing
      if (lane < 8) s_alpha[w][cn][lane] = 0.f;
      if (lane == 0) s_srcw[w][cn] = 0;
      cpad = cn + 1;
    }
    // feature pass: 2 edge rows per step (one per half-wave)
    for (int c = half; c < cpad; c += 2) {
      const int sc = s_srcw[w][c];
      const float a = s_alpha[w][c][myh];
      const uint4 d = *(const uint4*)&featb[(size_t)sc * HF + fo];
      facc[0] = fmaf(a, bf2f_lo(d.x), facc[0]);
      facc[1] = fmaf(a, bf2f_hi(d.x), facc[1]);
      facc[2] = fmaf(a, bf2f_lo(d.y), facc[2]);
      facc[3] = fmaf(a, bf2f_hi(d.y), facc[3]);
      facc[4] = fmaf(a, bf2f_lo(d.z), facc[4]);
      facc[5] = fmaf(a, bf2f_hi(d.z), facc[5]);
      facc[6] = fmaf(a, bf2f_lo(d.w), facc[6]);
      facc[7] = fmaf(a, bf2f_hi(d.w), facc[7]);
    }
  }

  // softmax denominator per head (reduce over the 8 edge-slots)
  ssum += __shfl_xor(ssum, 8, 64);
  ssum += __shfl_xor(ssum, 16, 64);
  ssum += __shfl_xor(ssum, 32, 64);
  const float inv = 1.0f / ssum;                       // for head h
  const float invmy = __shfl(inv, (lane & 32) | myh, 64);  // for head myh

  // combine half-waves (partner holds same feature slice, other edges)
#pragma unroll
  for (int i = 0; i < 8; ++i) facc[i] += __shfl_xor(facc[i], 32, 64);

  if (lane < 32) {
    float4 r0 = make_float4(facc[0] * invmy, facc[1] * invmy,
                            facc[2] * invmy, facc[3] * invmy);
    float4 r1 = make_float4(facc[4] * invmy, facc[5] * invmy,
                            facc[6] * invmy, facc[7] * invmy);
    *(float4*)&out[(size_t)v * HF + fo] = r0;
    *(float4*)&out[(size_t)v * HF + fo + 4] = r1;
  }
}

// ---------------------------------------------------------------------------
extern "C" void kernel_launch(void* const* d_in, const int* in_sizes, int n_in,
                              void* d_out, int out_size, void* d_ws,
                              size_t ws_size, hipStream_t stream) {
  const float* feat = (const float*)d_in[0];
  const float* fc_w = (const float*)d_in[1];
  const float* attn_l = (const float*)d_in[2];
  // d_in[3] = attn_r: unused — cancels exactly in the edge softmax.
  const int* src = (const int*)d_in[4];
  const int* dst = (const int*)d_in[5];
  float* out = (float*)d_out;

  const int N = N_NODES;
  const int E = N_EDGES;

  // workspace layout (~27.5 MB)
  ushort* featb = (ushort*)d_ws;                    // N*256 bf16  (25.6 MB)
  float* el = (float*)(featb + (size_t)N * HF);     // N*8 f32     (1.6 MB)
  ushort* Bt = (ushort*)(el + (size_t)N * HEADS);   // 256*256 bf16 (128 KB)
  int* row_ptr = (int*)(Bt + (size_t)IN_F * HF);    // N+1 ints

  transpose_w<<<HF, IN_F, 0, stream>>>(fc_w, Bt);
  rowptr_kernel<<<(N + 1 + 255) / 256, 256, 0, stream>>>(dst, row_ptr, N, E);

  dim3 gg((N + 127) / 128, 2);
  gemm_regB<<<gg, 512, 0, stream>>>(feat, Bt, featb, N);

  scores_kernel<<<(N * HEADS + 255) / 256, 256, 0, stream>>>(featb, attn_l,
                                                             el, N * HEADS);

  aggregate_kernel<<<(N + 3) / 4, 256, 0, stream>>>(featb, el, src, row_ptr,
                                                    out);
}